// Round 9
// baseline (435.682 us; speedup 1.0000x reference)
//
#include <hip/hip_runtime.h>
#include <hip/hip_bf16.h>

#define DEV_INLINE __device__ __forceinline__

static constexpr int WAVE = 64;
static constexpr float FP8_SCALE = 64.0f;
static constexpr float FP8_INV   = 1.0f / 64.0f;

typedef float floatx2 __attribute__((ext_vector_type(2)));

DEV_INLINE float wave_max(float v) {
    #pragma unroll
    for (int o = 32; o > 0; o >>= 1) v = fmaxf(v, __shfl_xor(v, o));
    return v;
}
DEV_INLINE float wave_sum(float v) {
    #pragma unroll
    for (int o = 32; o > 0; o >>= 1) v += __shfl_xor(v, o);
    return v;
}
DEV_INLINE float leaky02(float x) { return x > 0.f ? x : 0.2f * x; }
DEV_INLINE unsigned short f2b(float f) {
    __hip_bfloat16 b = __float2bfloat16(f);
    return *reinterpret_cast<unsigned short*>(&b);
}
DEV_INLINE float b2f(unsigned short u) {
    unsigned int x = ((unsigned int)u) << 16;
    return __uint_as_float(x);
}

// ---------------- CSR build ----------------
__global__ void count_kernel(const int* __restrict__ ei, int E, int* __restrict__ deg) {
    int i = blockIdx.x * blockDim.x + threadIdx.x;
    if (i >= E) return;
    atomicAdd(&deg[ei[E + i]], 1);
}

__global__ __launch_bounds__(256)
void scan_partial_kernel(const int* __restrict__ deg, int* __restrict__ blocksum, int n) {
    int t = threadIdx.x;
    int base = blockIdx.x * 1024 + t * 4;
    int s = 0;
    #pragma unroll
    for (int j = 0; j < 4; ++j) { int i = base + j; if (i < n) s += deg[i]; }
    __shared__ int red[4];
    s = (int)wave_sum((float)s);
    if ((t & 63) == 0) red[t >> 6] = s;
    __syncthreads();
    if (t == 0) blocksum[blockIdx.x] = red[0] + red[1] + red[2] + red[3];
}

__global__ __launch_bounds__(64)
void scan_blocksum_kernel(int* __restrict__ blocksum, int* __restrict__ off, int nblk, int n) {
    int lane = threadIdx.x;
    int v = (lane < nblk) ? blocksum[lane] : 0;
    int orig = v;
    #pragma unroll
    for (int o = 1; o < 64; o <<= 1) {
        int u = __shfl_up(v, o);
        if (lane >= o) v += u;
    }
    if (lane < nblk) blocksum[lane] = v - orig;
    if (lane == 63) off[n] = v;
}

__global__ __launch_bounds__(256)
void scan_final_kernel(const int* __restrict__ deg, const int* __restrict__ blockoff,
                       int* __restrict__ off, int* __restrict__ cursor, int n) {
    int t = threadIdx.x, lane = t & 63, wid = t >> 6;
    int base = blockIdx.x * 1024 + t * 4;
    int v[4], s = 0;
    #pragma unroll
    for (int j = 0; j < 4; ++j) {
        int i = base + j;
        v[j] = (i < n) ? deg[i] : 0;
        s += v[j];
    }
    int incl = s;
    #pragma unroll
    for (int o = 1; o < 64; o <<= 1) {
        int u = __shfl_up(incl, o);
        if (lane >= o) incl += u;
    }
    __shared__ int wtot[4];
    if (lane == 63) wtot[wid] = incl;
    __syncthreads();
    int woff = 0;
    for (int w0 = 0; w0 < wid; ++w0) woff += wtot[w0];
    int run = blockoff[blockIdx.x] + woff + incl - s;
    #pragma unroll
    for (int j = 0; j < 4; ++j) {
        int i = base + j;
        if (i < n) { off[i] = run; cursor[i] = run; }
        run += v[j];
    }
}

// fill: CSR edge list + src array in CSR order
__global__ void fill_kernel(const int* __restrict__ ei, int E,
                            int* __restrict__ cursor, int* __restrict__ ce,
                            int* __restrict__ esrc) {
    int i = blockIdx.x * blockDim.x + threadIdx.x;
    if (i >= E) return;
    int d = ei[E + i];
    int pos = atomicAdd(&cursor[d], 1);
    ce[pos] = i;
    esrc[pos] = ei[i];
}

// one-time: ea_csr[pos] = ea[ce[pos]]  (random read, sequential write)
__global__ void reorder_ea_kernel(const int* __restrict__ ce, const float* __restrict__ ea,
                                  float* __restrict__ ea_csr, int E) {
    int pos = blockIdx.x * blockDim.x + threadIdx.x;
    if (pos >= E) return;
    int e = ce[pos];
    const float4* p = reinterpret_cast<const float4*>(ea + (size_t)e * 8);
    float4 a0 = p[0], a1 = p[1];
    float4* q = reinterpret_cast<float4*>(ea_csr + (size_t)pos * 8);
    q[0] = a0; q[1] = a1;
}

// ---------------- watt[k] = sum_h We[k,h]*att[h], watt[8] = be.att ----------------
__global__ void watt_kernel(const float* __restrict__ We, const float* __restrict__ att,
                            const float* __restrict__ be, float* __restrict__ watt, int H) {
    int lane = threadIdx.x;
    for (int k = 0; k < 8; ++k) {
        float s = 0.f;
        for (int h = lane; h < H; h += WAVE) s += We[k * H + h] * att[h];
        s = wave_sum(s);
        if (lane == 0) watt[k] = s;
    }
    float s = 0.f;
    for (int h = lane; h < H; h += WAVE) s += be[h] * att[h];
    s = wave_sum(s);
    if (lane == 0) watt[8] = s;
}

// ---------------- per-layer streaming scores in CSR order ----------------
// sc_csr[pos] = leaky( nscore[esrc[pos]] + ea_csr[pos].watt + watt[8] )
__global__ void score_csr_kernel(const int* __restrict__ esrc, const float* __restrict__ ea_csr,
                                 const float* __restrict__ watt, const float* __restrict__ nscore,
                                 float* __restrict__ sc_csr, int E) {
    int pos = blockIdx.x * blockDim.x + threadIdx.x;
    if (pos >= E) return;
    const float4* p = reinterpret_cast<const float4*>(ea_csr + (size_t)pos * 8);
    float4 a0 = p[0], a1 = p[1];
    float s = watt[8];
    s += a0.x * watt[0] + a0.y * watt[1] + a0.z * watt[2] + a0.w * watt[3];
    s += a1.x * watt[4] + a1.y * watt[5] + a1.z * watt[6] + a1.w * watt[7];
    sc_csr[pos] = leaky02(nscore[esrc[pos]] + s);
}

// ---------------- node linear (LDS-tiled register-blocked GEMM) ----------------
template <int H, int NB, bool INBF16>
__global__ __launch_bounds__(256)
void nodelin_kernel(const float* __restrict__ hf, const unsigned short* __restrict__ hb,
                    const int* __restrict__ xidx,
                    const float* __restrict__ Wm, const float* __restrict__ bm,
                    const float* __restrict__ Ws, const float* __restrict__ bs,
                    const float* __restrict__ att,
                    unsigned char* __restrict__ hWm8, unsigned short* __restrict__ hWsb,
                    float* __restrict__ nscore, int n) {
    constexpr int F4  = H / 4;
    constexpr int NC  = 256 / F4;
    constexpr int NPT = NB / NC;
    constexpr int LDW = 68;
    __shared__ float sh[NB][LDW];
    int n0 = blockIdx.x * NB;
    int tid = threadIdx.x;

    for (int i = tid; i < NB * 16; i += 256) {
        int node = i >> 4, q = i & 15;
        int row = n0 + node;
        float4 v = make_float4(0.f, 0.f, 0.f, 0.f);
        if (row < n) {
            if constexpr (INBF16) {
                ushort4 u = reinterpret_cast<const ushort4*>(hb + (size_t)row * 64)[q];
                v = make_float4(b2f(u.x), b2f(u.y), b2f(u.z), b2f(u.w));
            } else {
                int src = xidx ? xidx[row] : row;
                v = reinterpret_cast<const float4*>(hf + (size_t)src * 64)[q];
            }
        }
        reinterpret_cast<float4*>(&sh[node][0])[q] = v;
    }
    __syncthreads();

    int f4 = (tid % F4) * 4;
    int j0 = tid / F4;
    float4 am[NPT], as[NPT];
    float4 bm4 = *reinterpret_cast<const float4*>(bm + f4);
    float4 bs4 = *reinterpret_cast<const float4*>(bs + f4);
    #pragma unroll
    for (int p = 0; p < NPT; ++p) { am[p] = bm4; as[p] = bs4; }

    for (int k4 = 0; k4 < 16; ++k4) {
        float4 hv[NPT];
        #pragma unroll
        for (int p = 0; p < NPT; ++p)
            hv[p] = reinterpret_cast<const float4*>(&sh[j0 + p * NC][0])[k4];
        #pragma unroll
        for (int kk = 0; kk < 4; ++kk) {
            int k = k4 * 4 + kk;
            float4 wm = *reinterpret_cast<const float4*>(Wm + k * H + f4);
            float4 ws = *reinterpret_cast<const float4*>(Ws + k * H + f4);
            #pragma unroll
            for (int p = 0; p < NPT; ++p) {
                float hk = (&hv[p].x)[kk];
                am[p].x += hk * wm.x; am[p].y += hk * wm.y;
                am[p].z += hk * wm.z; am[p].w += hk * wm.w;
                as[p].x += hk * ws.x; as[p].y += hk * ws.y;
                as[p].z += hk * ws.z; as[p].w += hk * ws.w;
            }
        }
    }

    float4 at4 = *reinterpret_cast<const float4*>(att + f4);
    #pragma unroll
    for (int p = 0; p < NPT; ++p) {
        int row = n0 + j0 + p * NC;
        float sc = am[p].x * at4.x + am[p].y * at4.y + am[p].z * at4.z + am[p].w * at4.w;
        #pragma unroll
        for (int o = 1; o < F4; o <<= 1) sc += __shfl_xor(sc, o);
        if (row < n) {
            int pk = 0;
            pk = __builtin_amdgcn_cvt_pk_fp8_f32(am[p].x * FP8_SCALE, am[p].y * FP8_SCALE, pk, false);
            pk = __builtin_amdgcn_cvt_pk_fp8_f32(am[p].z * FP8_SCALE, am[p].w * FP8_SCALE, pk, true);
            *reinterpret_cast<unsigned int*>(hWm8 + (size_t)row * H + f4) = (unsigned int)pk;
            ushort4 sb;
            sb.x = f2b(as[p].x); sb.y = f2b(as[p].y); sb.z = f2b(as[p].z); sb.w = f2b(as[p].w);
            *reinterpret_cast<ushort4*>(hWsb + (size_t)row * H + f4) = sb;
            if ((tid % F4) == 0) nscore[row] = sc;
        }
    }
}

// ---------------- aggregation: sequential edge streams + random fp8 row gather ----------------
template <int H>
__global__ __launch_bounds__(64)
void agg_kernel(const int* __restrict__ csr_off,
                const int* __restrict__ esrc, const float* __restrict__ sc_csr,
                const float* __restrict__ ea_csr,
                const float* __restrict__ We, const float* __restrict__ be,
                const unsigned char* __restrict__ hWm8, const unsigned short* __restrict__ hWsb,
                unsigned short* __restrict__ hout, int n) {
    constexpr int PE   = (H == 128) ? 2 : 4;
    constexpr int LSUB = 64 / PE;
    int node = blockIdx.x;
    int lane = threadIdx.x;
    int sub = lane / LSUB;
    int fo  = lane % LSUB;
    int off0 = csr_off[node];
    int deg = csr_off[node + 1] - off0;

    if (deg == 0) {
        if (lane < LSUB) {
            ushort4 hs = *reinterpret_cast<const ushort4*>(hWsb + (size_t)node * H + 4 * fo);
            ushort4 ob;
            ob.x = f2b(fmaxf(b2f(hs.x), 0.f));
            ob.y = f2b(fmaxf(b2f(hs.y), 0.f));
            ob.z = f2b(fmaxf(b2f(hs.z), 0.f));
            ob.w = f2b(fmaxf(b2f(hs.w), 0.f));
            *reinterpret_cast<ushort4*>(hout + (size_t)node * H + 4 * fo) = ob;
        }
        return;
    }

    float cea[8];
    #pragma unroll
    for (int k = 0; k < 8; ++k) cea[k] = 0.f;
    float acc4[4] = {0.f, 0.f, 0.f, 0.f};

    auto accum_chunk = [&](int s_, float cf, int cnt) {
        for (int j0 = 0; j0 < cnt; j0 += PE) {
            int j = j0 + sub;
            int sj = __shfl(s_, j & 63);
            float cj = __shfl(cf, j & 63);
            if (j >= cnt) cj = 0.f;
            unsigned int g = *reinterpret_cast<const unsigned int*>(
                hWm8 + (size_t)sj * H + 4 * fo);
            floatx2 lo = __builtin_amdgcn_cvt_pk_f32_fp8(g, false);
            floatx2 hi = __builtin_amdgcn_cvt_pk_f32_fp8(g, true);
            acc4[0] += cj * lo[0];
            acc4[1] += cj * lo[1];
            acc4[2] += cj * hi[0];
            acc4[3] += cj * hi[1];
        }
    };

    if (deg <= WAVE) {
        int s_ = 0;
        float a = -1e30f;
        if (lane < deg) {
            s_ = esrc[off0 + lane];
            a = sc_csr[off0 + lane];
        }
        float mx = wave_max(a);
        float cf = (lane < deg) ? expf(a - mx) : 0.f;
        float ssum = wave_sum(cf);
        cf *= 1.f / (ssum + 1e-16f);
        if (lane < deg) {
            const float4* p = reinterpret_cast<const float4*>(ea_csr + (size_t)(off0 + lane) * 8);
            float4 a0 = p[0], a1 = p[1];
            cea[0] = cf * a0.x; cea[1] = cf * a0.y; cea[2] = cf * a0.z; cea[3] = cf * a0.w;
            cea[4] = cf * a1.x; cea[5] = cf * a1.y; cea[6] = cf * a1.z; cea[7] = cf * a1.w;
        }
        accum_chunk(s_, cf, deg);
    } else {
        float mx = -1e30f;
        for (int base = 0; base < deg; base += WAVE) {
            int i = base + lane;
            if (i < deg) mx = fmaxf(mx, sc_csr[off0 + i]);
        }
        mx = wave_max(mx);
        float ssum = 0.f;
        for (int base = 0; base < deg; base += WAVE) {
            int i = base + lane;
            if (i < deg) ssum += expf(sc_csr[off0 + i] - mx);
        }
        ssum = wave_sum(ssum);
        float invs = 1.f / (ssum + 1e-16f);
        for (int base = 0; base < deg; base += WAVE) {
            int cnt = min(WAVE, deg - base);
            int i = base + lane;
            int s_ = 0;
            float cf = 0.f;
            if (i < deg) {
                s_ = esrc[off0 + i];
                cf = expf(sc_csr[off0 + i] - mx) * invs;
                const float4* p = reinterpret_cast<const float4*>(ea_csr + (size_t)(off0 + i) * 8);
                float4 a0 = p[0], a1 = p[1];
                cea[0] += cf * a0.x; cea[1] += cf * a0.y; cea[2] += cf * a0.z; cea[3] += cf * a0.w;
                cea[4] += cf * a1.x; cea[5] += cf * a1.y; cea[6] += cf * a1.z; cea[7] += cf * a1.w;
            }
            accum_chunk(s_, cf, cnt);
        }
    }

    #pragma unroll
    for (int k = 0; k < 4; ++k) {
        if (PE == 4) acc4[k] += __shfl_xor(acc4[k], 16);
        acc4[k] += __shfl_xor(acc4[k], 32);
    }
    #pragma unroll
    for (int k = 0; k < 8; ++k) cea[k] = wave_sum(cea[k]);

    if (lane < LSUB) {
        float invdeg = 1.f / (float)deg;
        ushort4 hs = *reinterpret_cast<const ushort4*>(hWsb + (size_t)node * H + 4 * fo);
        float sk[4] = {b2f(hs.x), b2f(hs.y), b2f(hs.z), b2f(hs.w)};
        ushort4 ob;
        unsigned short* obp = &ob.x;
        #pragma unroll
        for (int k = 0; k < 4; ++k) {
            int f = 4 * fo + k;
            float ew = be[f];
            #pragma unroll
            for (int k8 = 0; k8 < 8; ++k8) ew += cea[k8] * We[k8 * H + f];
            float v = (acc4[k] * FP8_INV + ew) * invdeg + sk[k];
            obp[k] = f2b(fmaxf(v, 0.f));
        }
        *reinterpret_cast<ushort4*>(hout + (size_t)node * H + 4 * fo) = ob;
    }
}

// ---------------- graph counts via binary search on sorted batchh ----------------
__global__ void graph_cnt_kernel(const int* __restrict__ batchh, int* __restrict__ gcnt,
                                 int n, int G) {
    int b = blockIdx.x * blockDim.x + threadIdx.x;
    if (b >= G) return;
    auto lb = [&](int key) {
        int lo = 0, hi = n;
        while (lo < hi) {
            int mid = (lo + hi) >> 1;
            if (batchh[mid] < key) lo = mid + 1; else hi = mid;
        }
        return lo;
    };
    gcnt[b] = lb(b + 1) - lb(b);
}

__global__ __launch_bounds__(128)
void pool_sum_kernel(const unsigned short* __restrict__ h, const int* __restrict__ batchh,
                     float* __restrict__ gsum, int n) {
    int f = threadIdx.x;
    int chunk = (n + gridDim.x - 1) / gridDim.x;
    int start = blockIdx.x * chunk;
    int end = min(n, start + chunk);
    if (start >= end) return;
    float acc = 0.f;
    int cur = batchh[start];
    for (int node = start; node < end; ++node) {
        int b = batchh[node];
        if (b != cur) {
            atomicAdd(&gsum[cur * 128 + f], acc);
            acc = 0.f;
            cur = b;
        }
        acc += b2f(h[(size_t)node * 128 + f]);
    }
    atomicAdd(&gsum[cur * 128 + f], acc);
}

// ---------------- classifier ----------------
__global__ __launch_bounds__(128)
void classifier_kernel(const float* __restrict__ gsum, const int* __restrict__ gcnt,
                       const float* __restrict__ Wc1, const float* __restrict__ bc1,
                       const float* __restrict__ Wc2, const float* __restrict__ bc2,
                       float* __restrict__ out) {
    int b = blockIdx.x;
    int f = threadIdx.x;
    __shared__ float gm[128];
    __shared__ float t1[128];
    float c = (float)max(gcnt[b], 1);
    gm[f] = gsum[b * 128 + f] / c;
    __syncthreads();
    float acc = bc1[f];
    for (int k = 0; k < 128; ++k) acc += gm[k] * Wc1[k * 128 + f];
    t1[f] = fmaxf(acc, 0.f);
    __syncthreads();
    if (f < 4) {
        float o = bc2[f];
        for (int k = 0; k < 128; ++k) o += t1[k] * Wc2[k * 4 + f];
        out[b * 4 + f] = o;
    }
}

extern "C" void kernel_launch(void* const* d_in, const int* in_sizes, int n_in,
                              void* d_out, int out_size, void* d_ws, size_t ws_size,
                              hipStream_t stream) {
    const int* x      = (const int*)d_in[0];
    const int* ei     = (const int*)d_in[1];
    const float* ea   = (const float*)d_in[2];
    const int* batchh = (const int*)d_in[3];
    const float* emb  = (const float*)d_in[4];
    const float* Wm0 = (const float*)d_in[5];  const float* bm0 = (const float*)d_in[6];
    const float* We0 = (const float*)d_in[7];  const float* be0 = (const float*)d_in[8];
    const float* att0 = (const float*)d_in[9];
    const float* Ws0 = (const float*)d_in[10]; const float* bs0 = (const float*)d_in[11];
    const float* Wm1 = (const float*)d_in[12]; const float* bm1 = (const float*)d_in[13];
    const float* We1 = (const float*)d_in[14]; const float* be1 = (const float*)d_in[15];
    const float* att1 = (const float*)d_in[16];
    const float* Ws1 = (const float*)d_in[17]; const float* bs1 = (const float*)d_in[18];
    const float* Wc1 = (const float*)d_in[19]; const float* bc1 = (const float*)d_in[20];
    const float* Wc2 = (const float*)d_in[21]; const float* bc2 = (const float*)d_in[22];

    const int N = in_sizes[0];
    const int E = in_sizes[1] / 2;
    const int G = 64;
    const int H2 = 128;

    char* w = (char*)d_ws;
    auto alloc = [&](size_t bytes) -> void* {
        void* p = (void*)w;
        w += (bytes + 255) & ~(size_t)255;
        return p;
    };
    unsigned short* hbuf = (unsigned short*)alloc((size_t)N * 128 * 2);
    unsigned char* hWm8  = (unsigned char*)alloc((size_t)N * 128);
    unsigned short* hWsb = (unsigned short*)alloc((size_t)N * 128 * 2);
    float* nscore        = (float*)alloc((size_t)N * 4);
    float* ea_csr        = (float*)alloc((size_t)E * 8 * 4);
    float* sc_csr        = (float*)alloc((size_t)E * 4);
    int* esrc            = (int*)alloc((size_t)E * 4);
    int* degcnt          = (int*)alloc((size_t)N * 4);
    int* csroff          = (int*)alloc((size_t)(N + 1) * 4);
    int* cursor          = (int*)alloc((size_t)N * 4);
    int* ce              = (int*)alloc((size_t)E * 4);
    float* watt          = (float*)alloc(16 * 4);
    float* gsum          = (float*)alloc((size_t)G * H2 * 4);
    int* gcnt            = (int*)alloc((size_t)G * 4);
    int* blocksum        = (int*)alloc(256 * 4);

    auto cdiv = [](int a, int b) { return (a + b - 1) / b; };
    const int NBLK = cdiv(N, 1024);

    (void)hipMemsetAsync(degcnt, 0, (size_t)N * 4, stream);
    (void)hipMemsetAsync(gsum, 0, (size_t)G * H2 * 4, stream);

    // CSR by dst (hierarchical scan) + CSR-ordered edge streams
    count_kernel<<<cdiv(E, 256), 256, 0, stream>>>(ei, E, degcnt);
    scan_partial_kernel<<<NBLK, 256, 0, stream>>>(degcnt, blocksum, N);
    scan_blocksum_kernel<<<1, 64, 0, stream>>>(blocksum, csroff, NBLK, N);
    scan_final_kernel<<<NBLK, 256, 0, stream>>>(degcnt, blocksum, csroff, cursor, N);
    fill_kernel<<<cdiv(E, 256), 256, 0, stream>>>(ei, E, cursor, ce, esrc);
    reorder_ea_kernel<<<cdiv(E, 256), 256, 0, stream>>>(ce, ea, ea_csr, E);

    // ---- layer 0: 64 -> 64 ----
    watt_kernel<<<1, 64, 0, stream>>>(We0, att0, be0, watt, 64);
    nodelin_kernel<64, 64, false><<<cdiv(N, 64), 256, 0, stream>>>(
        emb, nullptr, x, Wm0, bm0, Ws0, bs0, att0, hWm8, hWsb, nscore, N);
    score_csr_kernel<<<cdiv(E, 256), 256, 0, stream>>>(esrc, ea_csr, watt, nscore, sc_csr, E);
    agg_kernel<64><<<N, 64, 0, stream>>>(csroff, esrc, sc_csr, ea_csr,
                                         We0, be0, hWm8, hWsb, hbuf, N);

    // ---- layer 1: 64 -> 128 ----
    watt_kernel<<<1, 64, 0, stream>>>(We1, att1, be1, watt, 128);
    nodelin_kernel<128, 32, true><<<cdiv(N, 32), 256, 0, stream>>>(
        nullptr, hbuf, nullptr, Wm1, bm1, Ws1, bs1, att1, hWm8, hWsb, nscore, N);
    score_csr_kernel<<<cdiv(E, 256), 256, 0, stream>>>(esrc, ea_csr, watt, nscore, sc_csr, E);
    agg_kernel<128><<<N, 64, 0, stream>>>(csroff, esrc, sc_csr, ea_csr,
                                          We1, be1, hWm8, hWsb, hbuf, N);

    // ---- global mean pool + classifier ----
    graph_cnt_kernel<<<1, 64, 0, stream>>>(batchh, gcnt, N, G);
    pool_sum_kernel<<<512, 128, 0, stream>>>(hbuf, batchh, gsum, N);
    classifier_kernel<<<G, 128, 0, stream>>>(gsum, gcnt, Wc1, bc1, Wc2, bc2, (float*)d_out);
}

// Round 10
// 396.180 us; speedup vs baseline: 1.0997x; 1.0997x over previous
//
#include <hip/hip_runtime.h>
#include <hip/hip_bf16.h>

#define DEV_INLINE __device__ __forceinline__

static constexpr int WAVE = 64;
static constexpr float FP8_SCALE = 64.0f;
static constexpr float FP8_INV   = 1.0f / 64.0f;

typedef float floatx2 __attribute__((ext_vector_type(2)));

DEV_INLINE float wave_sum(float v) {
    #pragma unroll
    for (int o = 32; o > 0; o >>= 1) v += __shfl_xor(v, o);
    return v;
}
DEV_INLINE float leaky02(float x) { return x > 0.f ? x : 0.2f * x; }
DEV_INLINE unsigned short f2b(float f) {
    __hip_bfloat16 b = __float2bfloat16(f);
    return *reinterpret_cast<unsigned short*>(&b);
}
DEV_INLINE float b2f(unsigned short u) {
    unsigned int x = ((unsigned int)u) << 16;
    return __uint_as_float(x);
}

// ---------------- CSR build ----------------
__global__ void count_kernel(const int* __restrict__ ei, int E, int* __restrict__ deg) {
    int i = blockIdx.x * blockDim.x + threadIdx.x;
    if (i >= E) return;
    atomicAdd(&deg[ei[E + i]], 1);
}

__global__ __launch_bounds__(256)
void scan_partial_kernel(const int* __restrict__ deg, int* __restrict__ blocksum, int n) {
    int t = threadIdx.x;
    int base = blockIdx.x * 1024 + t * 4;
    int s = 0;
    #pragma unroll
    for (int j = 0; j < 4; ++j) { int i = base + j; if (i < n) s += deg[i]; }
    __shared__ int red[4];
    s = (int)wave_sum((float)s);
    if ((t & 63) == 0) red[t >> 6] = s;
    __syncthreads();
    if (t == 0) blocksum[blockIdx.x] = red[0] + red[1] + red[2] + red[3];
}

__global__ __launch_bounds__(64)
void scan_blocksum_kernel(int* __restrict__ blocksum, int* __restrict__ off, int nblk, int n) {
    int lane = threadIdx.x;
    int v = (lane < nblk) ? blocksum[lane] : 0;
    int orig = v;
    #pragma unroll
    for (int o = 1; o < 64; o <<= 1) {
        int u = __shfl_up(v, o);
        if (lane >= o) v += u;
    }
    if (lane < nblk) blocksum[lane] = v - orig;
    if (lane == 63) off[n] = v;
}

__global__ __launch_bounds__(256)
void scan_final_kernel(const int* __restrict__ deg, const int* __restrict__ blockoff,
                       int* __restrict__ off, int* __restrict__ cursor, int n) {
    int t = threadIdx.x, lane = t & 63, wid = t >> 6;
    int base = blockIdx.x * 1024 + t * 4;
    int v[4], s = 0;
    #pragma unroll
    for (int j = 0; j < 4; ++j) {
        int i = base + j;
        v[j] = (i < n) ? deg[i] : 0;
        s += v[j];
    }
    int incl = s;
    #pragma unroll
    for (int o = 1; o < 64; o <<= 1) {
        int u = __shfl_up(incl, o);
        if (lane >= o) incl += u;
    }
    __shared__ int wtot[4];
    if (lane == 63) wtot[wid] = incl;
    __syncthreads();
    int woff = 0;
    for (int w0 = 0; w0 < wid; ++w0) woff += wtot[w0];
    int run = blockoff[blockIdx.x] + woff + incl - s;
    #pragma unroll
    for (int j = 0; j < 4; ++j) {
        int i = base + j;
        if (i < n) { off[i] = run; cursor[i] = run; }
        run += v[j];
    }
}

// fill: CSR src + edge attributes in CSR order (ea read is sequential here)
__global__ void fill_kernel(const int* __restrict__ ei, const float* __restrict__ ea, int E,
                            int* __restrict__ cursor, int* __restrict__ esrc,
                            float* __restrict__ ea_csr) {
    int i = blockIdx.x * blockDim.x + threadIdx.x;
    if (i >= E) return;
    int d = ei[E + i];
    int pos = atomicAdd(&cursor[d], 1);
    esrc[pos] = ei[i];
    const float4* p = reinterpret_cast<const float4*>(ea + (size_t)i * 8);
    float4 a0 = p[0], a1 = p[1];
    float4* q = reinterpret_cast<float4*>(ea_csr + (size_t)pos * 8);
    q[0] = a0; q[1] = a1;
}

// ---------------- both layers' watt in one launch ----------------
// watt[L*16 + k] = sum_h We_L[k,h]*att_L[h]; watt[L*16+8] = be_L.att_L
__global__ void watt2_kernel(const float* __restrict__ We0, const float* __restrict__ att0,
                             const float* __restrict__ be0,
                             const float* __restrict__ We1, const float* __restrict__ att1,
                             const float* __restrict__ be1,
                             float* __restrict__ watt) {
    int L = blockIdx.x;
    const float* We  = L ? We1 : We0;
    const float* att = L ? att1 : att0;
    const float* be  = L ? be1 : be0;
    int H = L ? 128 : 64;
    int lane = threadIdx.x;
    for (int k = 0; k < 8; ++k) {
        float s = 0.f;
        for (int h = lane; h < H; h += WAVE) s += We[k * H + h] * att[h];
        s = wave_sum(s);
        if (lane == 0) watt[L * 16 + k] = s;
    }
    float s = 0.f;
    for (int h = lane; h < H; h += WAVE) s += be[h] * att[h];
    s = wave_sum(s);
    if (lane == 0) watt[L * 16 + 8] = s;
}

// ---------------- per-layer streaming scores in CSR order ----------------
__global__ void score_csr_kernel(const int* __restrict__ esrc, const float* __restrict__ ea_csr,
                                 const float* __restrict__ watt, const float* __restrict__ nscore,
                                 float* __restrict__ sc_csr, int E) {
    int pos = blockIdx.x * blockDim.x + threadIdx.x;
    if (pos >= E) return;
    const float4* p = reinterpret_cast<const float4*>(ea_csr + (size_t)pos * 8);
    float4 a0 = p[0], a1 = p[1];
    float s = watt[8];
    s += a0.x * watt[0] + a0.y * watt[1] + a0.z * watt[2] + a0.w * watt[3];
    s += a1.x * watt[4] + a1.y * watt[5] + a1.z * watt[6] + a1.w * watt[7];
    sc_csr[pos] = leaky02(nscore[esrc[pos]] + s);
}

// ---------------- node linear (LDS-tiled register-blocked GEMM) ----------------
template <int H, int NB, bool INBF16>
__global__ __launch_bounds__(256)
void nodelin_kernel(const float* __restrict__ hf, const unsigned short* __restrict__ hb,
                    const int* __restrict__ xidx,
                    const float* __restrict__ Wm, const float* __restrict__ bm,
                    const float* __restrict__ Ws, const float* __restrict__ bs,
                    const float* __restrict__ att,
                    unsigned char* __restrict__ hWm8, unsigned short* __restrict__ hWsb,
                    float* __restrict__ nscore, int n) {
    constexpr int F4  = H / 4;
    constexpr int NC  = 256 / F4;
    constexpr int NPT = NB / NC;
    constexpr int LDW = 68;
    __shared__ float sh[NB][LDW];
    int n0 = blockIdx.x * NB;
    int tid = threadIdx.x;

    for (int i = tid; i < NB * 16; i += 256) {
        int node = i >> 4, q = i & 15;
        int row = n0 + node;
        float4 v = make_float4(0.f, 0.f, 0.f, 0.f);
        if (row < n) {
            if constexpr (INBF16) {
                ushort4 u = reinterpret_cast<const ushort4*>(hb + (size_t)row * 64)[q];
                v = make_float4(b2f(u.x), b2f(u.y), b2f(u.z), b2f(u.w));
            } else {
                int src = xidx ? xidx[row] : row;
                v = reinterpret_cast<const float4*>(hf + (size_t)src * 64)[q];
            }
        }
        reinterpret_cast<float4*>(&sh[node][0])[q] = v;
    }
    __syncthreads();

    int f4 = (tid % F4) * 4;
    int j0 = tid / F4;
    float4 am[NPT], as[NPT];
    float4 bm4 = *reinterpret_cast<const float4*>(bm + f4);
    float4 bs4 = *reinterpret_cast<const float4*>(bs + f4);
    #pragma unroll
    for (int p = 0; p < NPT; ++p) { am[p] = bm4; as[p] = bs4; }

    for (int k4 = 0; k4 < 16; ++k4) {
        float4 hv[NPT];
        #pragma unroll
        for (int p = 0; p < NPT; ++p)
            hv[p] = reinterpret_cast<const float4*>(&sh[j0 + p * NC][0])[k4];
        #pragma unroll
        for (int kk = 0; kk < 4; ++kk) {
            int k = k4 * 4 + kk;
            float4 wm = *reinterpret_cast<const float4*>(Wm + k * H + f4);
            float4 ws = *reinterpret_cast<const float4*>(Ws + k * H + f4);
            #pragma unroll
            for (int p = 0; p < NPT; ++p) {
                float hk = (&hv[p].x)[kk];
                am[p].x += hk * wm.x; am[p].y += hk * wm.y;
                am[p].z += hk * wm.z; am[p].w += hk * wm.w;
                as[p].x += hk * ws.x; as[p].y += hk * ws.y;
                as[p].z += hk * ws.z; as[p].w += hk * ws.w;
            }
        }
    }

    float4 at4 = *reinterpret_cast<const float4*>(att + f4);
    #pragma unroll
    for (int p = 0; p < NPT; ++p) {
        int row = n0 + j0 + p * NC;
        float sc = am[p].x * at4.x + am[p].y * at4.y + am[p].z * at4.z + am[p].w * at4.w;
        #pragma unroll
        for (int o = 1; o < F4; o <<= 1) sc += __shfl_xor(sc, o);
        if (row < n) {
            int pk = 0;
            pk = __builtin_amdgcn_cvt_pk_fp8_f32(am[p].x * FP8_SCALE, am[p].y * FP8_SCALE, pk, false);
            pk = __builtin_amdgcn_cvt_pk_fp8_f32(am[p].z * FP8_SCALE, am[p].w * FP8_SCALE, pk, true);
            *reinterpret_cast<unsigned int*>(hWm8 + (size_t)row * H + f4) = (unsigned int)pk;
            ushort4 sb;
            sb.x = f2b(as[p].x); sb.y = f2b(as[p].y); sb.z = f2b(as[p].z); sb.w = f2b(as[p].w);
            *reinterpret_cast<ushort4*>(hWsb + (size_t)row * H + f4) = sb;
            if ((tid % F4) == 0) nscore[row] = sc;
        }
    }
}

// ---------------- aggregation: LSUB-lane subgroup per node ----------------
// H=128: 32 lanes/node (2 nodes/wave); H=64: 16 lanes/node (4 nodes/wave).
// Softmax stats chunked over the subgroup; j-loop uses subgroup-uniform L1-hot
// re-reads of sc/esrc with __expf recompute (no register caching, no shfl pairs).
template <int H>
__global__ __launch_bounds__(64)
void agg_kernel(const int* __restrict__ csr_off,
                const int* __restrict__ esrc, const float* __restrict__ sc_csr,
                const float* __restrict__ ea_csr,
                const float* __restrict__ We, const float* __restrict__ be,
                const unsigned char* __restrict__ hWm8, const unsigned short* __restrict__ hWsb,
                unsigned short* __restrict__ hout, int n) {
    constexpr int LSUB = (H == 128) ? 32 : 16;
    constexpr int NPN  = 64 / LSUB;
    int lane = threadIdx.x;
    int sg   = lane / LSUB;
    int l    = lane % LSUB;
    int node = blockIdx.x * NPN + sg;
    if (node >= n) return;
    int base = lane - l;  // subgroup base lane
    int off0 = csr_off[node];
    int deg  = csr_off[node + 1] - off0;

    if (deg == 0) {
        ushort4 hs = *reinterpret_cast<const ushort4*>(hWsb + (size_t)node * H + 4 * l);
        ushort4 ob;
        ob.x = f2b(fmaxf(b2f(hs.x), 0.f));
        ob.y = f2b(fmaxf(b2f(hs.y), 0.f));
        ob.z = f2b(fmaxf(b2f(hs.z), 0.f));
        ob.w = f2b(fmaxf(b2f(hs.w), 0.f));
        *reinterpret_cast<ushort4*>(hout + (size_t)node * H + 4 * l) = ob;
        return;
    }

    // softmax stats (chunked, generic for any deg)
    float mx = -1e30f;
    for (int i = l; i < deg; i += LSUB) mx = fmaxf(mx, sc_csr[off0 + i]);
    #pragma unroll
    for (int o = LSUB / 2; o > 0; o >>= 1) mx = fmaxf(mx, __shfl_xor(mx, o));
    float ssum = 0.f;
    for (int i = l; i < deg; i += LSUB) ssum += __expf(sc_csr[off0 + i] - mx);
    #pragma unroll
    for (int o = LSUB / 2; o > 0; o >>= 1) ssum += __shfl_xor(ssum, o);
    float invs = 1.f / (ssum + 1e-16f);

    int c8 = l & 7;  // this lane's cea channel
    float ceac = 0.f;
    float acc4[4] = {0.f, 0.f, 0.f, 0.f};
    for (int j = 0; j < deg; ++j) {
        int pos = off0 + j;
        int sj = esrc[pos];                       // subgroup-uniform load
        float cj = __expf(sc_csr[pos] - mx) * invs;  // subgroup-uniform + cheap exp
        unsigned int g = *reinterpret_cast<const unsigned int*>(
            hWm8 + (size_t)sj * H + 4 * l);       // the one random gather
        floatx2 lo = __builtin_amdgcn_cvt_pk_f32_fp8(g, false);
        floatx2 hi = __builtin_amdgcn_cvt_pk_f32_fp8(g, true);
        acc4[0] += cj * lo[0];
        acc4[1] += cj * lo[1];
        acc4[2] += cj * hi[0];
        acc4[3] += cj * hi[1];
        ceac += cj * ea_csr[(size_t)pos * 8 + c8];
    }
    // reduce cea channel across duplicate lanes within the subgroup
    ceac += __shfl_xor(ceac, 8);
    if (LSUB == 32) ceac += __shfl_xor(ceac, 16);
    // broadcast all 8 channels to every lane of the subgroup
    float cea_k[8];
    #pragma unroll
    for (int k = 0; k < 8; ++k) cea_k[k] = __shfl(ceac, base + k);

    float invdeg = 1.f / (float)deg;
    ushort4 hs = *reinterpret_cast<const ushort4*>(hWsb + (size_t)node * H + 4 * l);
    float sk[4] = {b2f(hs.x), b2f(hs.y), b2f(hs.z), b2f(hs.w)};
    ushort4 ob;
    unsigned short* obp = &ob.x;
    #pragma unroll
    for (int k = 0; k < 4; ++k) {
        int f = 4 * l + k;
        float ew = be[f];
        #pragma unroll
        for (int k8 = 0; k8 < 8; ++k8) ew += cea_k[k8] * We[k8 * H + f];
        float v = (acc4[k] * FP8_INV + ew) * invdeg + sk[k];
        obp[k] = f2b(fmaxf(v, 0.f));
    }
    *reinterpret_cast<ushort4*>(hout + (size_t)node * H + 4 * l) = ob;
}

// ---------------- pooling ----------------
__global__ __launch_bounds__(128)
void pool_sum_kernel(const unsigned short* __restrict__ h, const int* __restrict__ batchh,
                     float* __restrict__ gsum, int n) {
    int f = threadIdx.x;
    int chunk = (n + gridDim.x - 1) / gridDim.x;
    int start = blockIdx.x * chunk;
    int end = min(n, start + chunk);
    if (start >= end) return;
    float acc = 0.f;
    int cur = batchh[start];
    for (int node = start; node < end; ++node) {
        int b = batchh[node];
        if (b != cur) {
            atomicAdd(&gsum[cur * 128 + f], acc);
            acc = 0.f;
            cur = b;
        }
        acc += b2f(h[(size_t)node * 128 + f]);
    }
    atomicAdd(&gsum[cur * 128 + f], acc);
}

// ---------------- classifier (graph count fused via binary search) ----------------
__global__ __launch_bounds__(128)
void classifier_kernel(const float* __restrict__ gsum, const int* __restrict__ batchh, int n,
                       const float* __restrict__ Wc1, const float* __restrict__ bc1,
                       const float* __restrict__ Wc2, const float* __restrict__ bc2,
                       float* __restrict__ out) {
    int b = blockIdx.x;
    int f = threadIdx.x;
    __shared__ float gm[128];
    __shared__ float t1[128];
    __shared__ int cnt;
    if (f == 0) {
        auto lb = [&](int key) {
            int lo = 0, hi = n;
            while (lo < hi) {
                int mid = (lo + hi) >> 1;
                if (batchh[mid] < key) lo = mid + 1; else hi = mid;
            }
            return lo;
        };
        cnt = lb(b + 1) - lb(b);
    }
    __syncthreads();
    float c = (float)max(cnt, 1);
    gm[f] = gsum[b * 128 + f] / c;
    __syncthreads();
    float acc = bc1[f];
    for (int k = 0; k < 128; ++k) acc += gm[k] * Wc1[k * 128 + f];
    t1[f] = fmaxf(acc, 0.f);
    __syncthreads();
    if (f < 4) {
        float o = bc2[f];
        for (int k = 0; k < 128; ++k) o += t1[k] * Wc2[k * 4 + f];
        out[b * 4 + f] = o;
    }
}

extern "C" void kernel_launch(void* const* d_in, const int* in_sizes, int n_in,
                              void* d_out, int out_size, void* d_ws, size_t ws_size,
                              hipStream_t stream) {
    const int* x      = (const int*)d_in[0];
    const int* ei     = (const int*)d_in[1];
    const float* ea   = (const float*)d_in[2];
    const int* batchh = (const int*)d_in[3];
    const float* emb  = (const float*)d_in[4];
    const float* Wm0 = (const float*)d_in[5];  const float* bm0 = (const float*)d_in[6];
    const float* We0 = (const float*)d_in[7];  const float* be0 = (const float*)d_in[8];
    const float* att0 = (const float*)d_in[9];
    const float* Ws0 = (const float*)d_in[10]; const float* bs0 = (const float*)d_in[11];
    const float* Wm1 = (const float*)d_in[12]; const float* bm1 = (const float*)d_in[13];
    const float* We1 = (const float*)d_in[14]; const float* be1 = (const float*)d_in[15];
    const float* att1 = (const float*)d_in[16];
    const float* Ws1 = (const float*)d_in[17]; const float* bs1 = (const float*)d_in[18];
    const float* Wc1 = (const float*)d_in[19]; const float* bc1 = (const float*)d_in[20];
    const float* Wc2 = (const float*)d_in[21]; const float* bc2 = (const float*)d_in[22];

    const int N = in_sizes[0];
    const int E = in_sizes[1] / 2;
    const int G = 64;
    const int H2 = 128;

    char* w = (char*)d_ws;
    auto alloc = [&](size_t bytes) -> void* {
        void* p = (void*)w;
        w += (bytes + 255) & ~(size_t)255;
        return p;
    };
    unsigned short* hbuf = (unsigned short*)alloc((size_t)N * 128 * 2);
    unsigned char* hWm8  = (unsigned char*)alloc((size_t)N * 128);
    unsigned short* hWsb = (unsigned short*)alloc((size_t)N * 128 * 2);
    float* nscore        = (float*)alloc((size_t)N * 4);
    float* ea_csr        = (float*)alloc((size_t)E * 8 * 4);
    float* sc_csr        = (float*)alloc((size_t)E * 4);
    int* esrc            = (int*)alloc((size_t)E * 4);
    int* degcnt          = (int*)alloc((size_t)N * 4);
    int* csroff          = (int*)alloc((size_t)(N + 1) * 4);
    int* cursor          = (int*)alloc((size_t)N * 4);
    float* watt          = (float*)alloc(32 * 4);
    float* gsum          = (float*)alloc((size_t)G * H2 * 4);
    int* blocksum        = (int*)alloc(256 * 4);

    auto cdiv = [](int a, int b) { return (a + b - 1) / b; };
    const int NBLK = cdiv(N, 1024);

    (void)hipMemsetAsync(degcnt, 0, (size_t)N * 4, stream);
    (void)hipMemsetAsync(gsum, 0, (size_t)G * H2 * 4, stream);

    // CSR by dst (hierarchical scan) + CSR-ordered edge streams (ea fused into fill)
    count_kernel<<<cdiv(E, 256), 256, 0, stream>>>(ei, E, degcnt);
    scan_partial_kernel<<<NBLK, 256, 0, stream>>>(degcnt, blocksum, N);
    scan_blocksum_kernel<<<1, 64, 0, stream>>>(blocksum, csroff, NBLK, N);
    scan_final_kernel<<<NBLK, 256, 0, stream>>>(degcnt, blocksum, csroff, cursor, N);
    fill_kernel<<<cdiv(E, 256), 256, 0, stream>>>(ei, ea, E, cursor, esrc, ea_csr);
    watt2_kernel<<<2, 64, 0, stream>>>(We0, att0, be0, We1, att1, be1, watt);

    // ---- layer 0: 64 -> 64 ----
    nodelin_kernel<64, 64, false><<<cdiv(N, 64), 256, 0, stream>>>(
        emb, nullptr, x, Wm0, bm0, Ws0, bs0, att0, hWm8, hWsb, nscore, N);
    score_csr_kernel<<<cdiv(E, 256), 256, 0, stream>>>(esrc, ea_csr, watt, nscore, sc_csr, E);
    agg_kernel<64><<<cdiv(N, 4), 64, 0, stream>>>(csroff, esrc, sc_csr, ea_csr,
                                                  We0, be0, hWm8, hWsb, hbuf, N);

    // ---- layer 1: 64 -> 128 ----
    nodelin_kernel<128, 32, true><<<cdiv(N, 32), 256, 0, stream>>>(
        nullptr, hbuf, nullptr, Wm1, bm1, Ws1, bs1, att1, hWm8, hWsb, nscore, N);
    score_csr_kernel<<<cdiv(E, 256), 256, 0, stream>>>(esrc, ea_csr, watt + 16, nscore, sc_csr, E);
    agg_kernel<128><<<cdiv(N, 2), 64, 0, stream>>>(csroff, esrc, sc_csr, ea_csr,
                                                   We1, be1, hWm8, hWsb, hbuf, N);

    // ---- global mean pool + classifier ----
    pool_sum_kernel<<<512, 128, 0, stream>>>(hbuf, batchh, gsum, N);
    classifier_kernel<<<G, 128, 0, stream>>>(gsum, batchh, N, Wc1, bc1, Wc2, bc2, (float*)d_out);
}